// Round 4
// baseline (531.885 us; speedup 1.0000x reference)
//
#include <hip/hip_runtime.h>
#include <hip/hip_bf16.h>

typedef unsigned short u16;
typedef unsigned int   u32;
typedef __attribute__((ext_vector_type(2))) float f32x2;
typedef __attribute__((ext_vector_type(4))) float f32x4;
typedef __attribute__((ext_vector_type(4))) u32   u32x4;
typedef __attribute__((ext_vector_type(8))) short bf16x8;

#define HWPIX  9216
#define NPIX   73728
#define LN_EPS 1e-5f
#define MROW   128      // pixels per block
#define ASTR   40       // afg row stride in elems (80B: 16B-aligned rows, 2-way-free banks)

__device__ __forceinline__ u16 f2bf(float f){
  u32 u = __builtin_bit_cast(u32, f);
  u += 0x7fffu + ((u >> 16) & 1u);          // RTNE
  return (u16)(u >> 16);
}
__device__ __forceinline__ float bfu2f(u16 h){ return __builtin_bit_cast(float, (u32)h << 16); }
__device__ __forceinline__ float fsigmoid(float v){ return __fdividef(1.f, 1.f + __expf(-v)); }
__device__ __forceinline__ float fsilu(float v){ return __fdividef(v, 1.f + __expf(-v)); }

__device__ __forceinline__ void gld16(const u16* g, u16* l){
  __builtin_amdgcn_global_load_lds((const __attribute__((address_space(1))) void*)g,
                                   (__attribute__((address_space(3))) void*)l,
                                   16, 0, 0);
}

// ---------------- kernel 1: weight convert into staging-order swizzled layout ------
// wsw[t][S][0..7] (u16): chunk t (0..47), slot S (0..1023). Slot S maps to
// B-col n = (S>>9)*128 + ((S>>6)&7)*16 + ((S>>2)&15), phys k-slot p = S&3,
// content k-quarter kq = p ^ ((((S>>2)&15)>>1)&3)  (XOR bank swizzle).
__global__ __launch_bounds__(256) void wconv(const float* __restrict__ pk,
                                             const float* __restrict__ gk,
                                             u16* __restrict__ wsw)
{
  int gid = blockIdx.x * 256 + threadIdx.x;   // 49152 total = 192 blocks
  int t = gid >> 10, S = gid & 1023;
  int q = (S >> 2) & 15, pp = S & 3, w8 = (S >> 6) & 7, rb = S >> 9;
  int n  = rb * 128 + w8 * 16 + q;
  int kq = pp ^ ((q >> 1) & 3);
  const float* W; int k0;
  if (t < 32) { W = pk; k0 = t * 32 + kq * 8; }
  else        { W = gk; k0 = (t - 32) * 32 + kq * 8; }
  u32 ow[4];
  #pragma unroll
  for (int e = 0; e < 4; ++e) {
    float f0 = W[(size_t)(k0 + 2*e)     * 256 + n];
    float f1 = W[(size_t)(k0 + 2*e + 1) * 256 + n];
    ow[e] = (u32)f2bf(f0) | ((u32)f2bf(f1) << 16);
  }
  *(u32x4*)(wsw + (size_t)gid * 8) = (u32x4){ow[0], ow[1], ow[2], ow[3]};
}

// ---------------- kernel 2: per-pixel LN stats + per-(b,h) partial sums ------------
__global__ __launch_bounds__(256) void prep(const float* __restrict__ x,
                                            const float* __restrict__ g,
                                            const float* __restrict__ bt,
                                            float* __restrict__ mu_rs,     // [73728][2]
                                            float* __restrict__ partial)   // [768][256]
{
  const int bh = blockIdx.x;
  const int tid = threadIdx.x;
  const int wv = tid >> 6, lane = tid & 63;
  const float* xrow = x + (size_t)bh * 96 * 256;
  __shared__ float red[4][256];

  f32x4 gv = *(const f32x4*)(g  + lane * 4);
  f32x4 bv = *(const f32x4*)(bt + lane * 4);
  f32x4 acc = {0.f, 0.f, 0.f, 0.f};

  for (int w = wv; w < 96; w += 4) {
    f32x4 v = *(const f32x4*)(xrow + w * 256 + lane * 4);
    float s  = v[0] + v[1] + v[2] + v[3];
    float s2 = v[0]*v[0] + v[1]*v[1] + v[2]*v[2] + v[3]*v[3];
    #pragma unroll
    for (int m = 1; m < 64; m <<= 1) { s += __shfl_xor(s, m); s2 += __shfl_xor(s2, m); }
    float mu  = s * (1.f / 256.f);
    float var = s2 * (1.f / 256.f) - mu * mu;
    float rs  = rsqrtf(var + LN_EPS);
    if (lane == 0) *(f32x2*)(mu_rs + (size_t)(bh * 96 + w) * 2) = f32x2{mu, rs};
    #pragma unroll
    for (int j = 0; j < 4; ++j) acc[j] += (v[j] - mu) * rs * gv[j] + bv[j];
  }
  *(f32x4*)(&red[wv][lane * 4]) = acc;
  __syncthreads();
  float s = red[0][tid] + red[1][tid] + red[2][tid] + red[3][tid];
  partial[(size_t)bh * 256 + tid] = s;
}

// ---------------- kernel 3: reduce rows -> spatial mean [8][258] (wrap-padded) -----
__global__ __launch_bounds__(256) void ln_mean(const float* __restrict__ partial,
                                               float* __restrict__ mean)
{
  int b = blockIdx.x, c = threadIdx.x;
  float s = 0.f;
  for (int h = 0; h < 96; ++h) s += partial[((size_t)b * 96 + h) * 256 + c];
  float m = s * (1.f / 9216.f);
  mean[b * 258 + c] = m;
  if (c < 2) mean[b * 258 + 256 + c] = m;
}

// ---------------- kernel 4: fused main ---------------------------------------------
// 128 pixels/block, 512 threads (8 waves 2x4, wave tile 64x64). Chunk-granular LDS:
// afg dbuf [2][128][40] + B ring [2][8192] -> 56KB -> 2 blocks/CU. h_norm recomputed
// per k-window from x + mu_rs (local in k). GEMM1 chunk order (window, comp) reuses
// the h-window registers across 4 comps. g_feat lives in bf16-packed regs.
__global__ __launch_bounds__(512, 4) void fused(
    const float* __restrict__ x,
    const float* __restrict__ lng, const float* __restrict__ lnb,
    const u16*  __restrict__ wsw, const float* __restrict__ mu_rs,
    const float* __restrict__ pbias, const float* __restrict__ gbias,
    const float* __restrict__ gamma, const float* __restrict__ meang,
    float* __restrict__ out)
{
  __shared__ u16 afg[2][MROW * ASTR];   // 20480 B
  __shared__ u16 Bl [2][8192];          // 32768 B
  __shared__ float gsh[256], bsh[256], msh[258];

  const int tid  = threadIdx.x;
  const long pix0 = (long)blockIdx.x * MROW;
  const int bat  = (int)(pix0 / HWPIX);      // 9216 % 128 == 0

  if (tid < 256) gsh[tid] = lng[tid];
  else           bsh[tid & 255] = lnb[tid & 255];
  if (tid < 258) msh[tid] = meang[bat * 258 + tid];

  const int wave = tid >> 6, lane = tid & 63;
  const int wr = wave & 1, wc = wave >> 1;       // 2x4 wave grid
  const int fr = lane & 15, kq = lane >> 4;
  const int r  = tid >> 2, q4 = tid & 3, jb = q4 * 8;   // A-build: row, 8-ch slice
  const int bswz = (kq ^ ((fr >> 1) & 3)) * 8;

  f32x4 acc[4][4];
  #pragma unroll
  for (int i = 0; i < 4; ++i)
    #pragma unroll
    for (int j = 0; j < 4; ++j) acc[i][j] = (f32x4){0.f, 0.f, 0.f, 0.f};
  u32 gfp[4][4][2];

  float h[10], mar[10];
  f32x4 xa, xb; f32x2 xc;
  const float* xrp = x + (pix0 + r) * 256;
  const f32x2 mr = *(const f32x2*)(mu_rs + (pix0 + r) * 2);

  auto stageB = [&](int u, int buf) {
    int wid = (u < 32) ? ((u & 3) * 8 + (u >> 2)) : u;
    const u16* src = wsw + (size_t)wid * 8192 + tid * 8;
    u16* dst = &Bl[buf][wave * 512];
    gld16(src, dst);
    gld16(src + 4096, dst + 4096);
  };
  auto xload = [&](int w) {                   // issue x loads for window w
    int cc = w * 32 + jb;
    xa = *(const f32x4*)(xrp + cc);
    xb = *(const f32x4*)(xrp + cc + 4);
    xc = (cc == 248) ? f32x2{xrp[0], xrp[1]} : *(const f32x2*)(xrp + cc + 8);
  };
  auto hmath = [&](int w) {                   // finish h_norm window + mean regs
    int cc = w * 32 + jb;
    float xv[10] = {xa[0],xa[1],xa[2],xa[3],xb[0],xb[1],xb[2],xb[3],xc[0],xc[1]};
    #pragma unroll
    for (int j = 0; j < 10; ++j) {
      int ch = (cc + j) & 255;
      h[j]   = (xv[j] - mr[0]) * mr[1] * gsh[ch] + bsh[ch];
      mar[j] = msh[cc + j];                   // padded: cc+9 <= 257 ok
    }
  };
  auto feats = [&](int comp, int buf) {       // Clifford component -> afg chunk
    const int s = 1 + (comp >> 1);
    u32 ow[4];
    #pragma unroll
    for (int j2 = 0; j2 < 4; ++j2) {
      int e0 = 2 * j2, e1 = 2 * j2 + 1;
      float r0, r1;
      if ((comp & 1) == 0) {
        r0 = fsilu(h[e0] * (h[e0 + s] - mar[e0 + s]));
        r1 = fsilu(h[e1] * (h[e1 + s] - mar[e1 + s]));
      } else {
        r0 = mar[e0] * h[e0 + s] - mar[e0 + s] * h[e0];
        r1 = mar[e1] * h[e1 + s] - mar[e1 + s] * h[e1];
      }
      ow[j2] = (u32)f2bf(r0) | ((u32)f2bf(r1) << 16);
    }
    *(u32x4*)(&afg[buf][r * ASTR + jb]) = (u32x4){ow[0], ow[1], ow[2], ow[3]};
  };
  auto znorm = [&](int buf) {                 // h_norm chunk (GEMM2 first K-half)
    u32 ow[4];
    #pragma unroll
    for (int j2 = 0; j2 < 4; ++j2)
      ow[j2] = (u32)f2bf(h[2*j2]) | ((u32)f2bf(h[2*j2+1]) << 16);
    *(u32x4*)(&afg[buf][r * ASTR + jb]) = (u32x4){ow[0], ow[1], ow[2], ow[3]};
  };
  auto gfcopy = [&](int cg, int buf) {        // g_feat chunk from regs (owning waves)
    if (wc == (cg >> 1)) {
      #pragma unroll
      for (int v = 0; v < 2; ++v) {
        int nt = (cg & 1) * 2 + v;
        #pragma unroll
        for (int ai = 0; ai < 4; ++ai)
          #pragma unroll
          for (int rp = 0; rp < 2; ++rp) {
            u32 pw = gfp[ai][nt][rp];
            int row0 = wr * 64 + ai * 16 + kq * 4 + rp * 2;
            afg[buf][row0 * ASTR + v * 16 + fr]       = (u16)pw;
            afg[buf][(row0 + 1) * ASTR + v * 16 + fr] = (u16)(pw >> 16);
          }
      }
    }
  };
  auto domfma = [&](int buf) {
    const u16* ar = &afg[buf][(wr * 64 + fr) * ASTR + kq * 8];
    bf16x8 av[4];
    #pragma unroll
    for (int ai = 0; ai < 4; ++ai) av[ai] = *(const bf16x8*)(ar + ai * 16 * ASTR);
    const u16* bp = &Bl[buf][wc * 2048 + fr * 32 + bswz];
    #pragma unroll
    for (int nt = 0; nt < 4; ++nt) {
      bf16x8 bv = *(const bf16x8*)(bp + nt * 512);
      #pragma unroll
      for (int ai = 0; ai < 4; ++ai)
        acc[ai][nt] = __builtin_amdgcn_mfma_f32_16x16x32_bf16(av[ai], bv, acc[ai][nt], 0, 0, 0);
    }
  };

  __syncthreads();                    // param LDS ready
  stageB(0, 0);
  xload(0); hmath(0);
  feats(0, 0);
  __syncthreads();                    // chunk 0 staged (drains gld16 + ds writes)

  #pragma unroll 2
  for (int t = 0; t < 48; ++t) {
    const int cb = t & 1, nb = cb ^ 1;
    const int u = t + 1;
    const bool needx = (u < 48) && ((u < 32) ? ((u & 3) == 0) : (u < 40));
    if (u < 48) stageB(u, nb);
    if (needx) xload((u < 32) ? (u >> 2) : (u - 32));     // T14: issue early
    domfma(cb);
    if (t == 31) {                    // epilogue 1: g_feat -> packed bf16 regs
      #pragma unroll
      for (int nt = 0; nt < 4; ++nt) {
        float pbv = pbias[wc * 64 + nt * 16 + fr];
        #pragma unroll
        for (int ai = 0; ai < 4; ++ai) {
          f32x4 a = acc[ai][nt];
          gfp[ai][nt][0] = (u32)f2bf(a[0] + pbv) | ((u32)f2bf(a[1] + pbv) << 16);
          gfp[ai][nt][1] = (u32)f2bf(a[2] + pbv) | ((u32)f2bf(a[3] + pbv) << 16);
          acc[ai][nt] = (f32x4){0.f, 0.f, 0.f, 0.f};
        }
      }
    }
    if (u < 48) {
      if (needx) hmath((u < 32) ? (u >> 2) : (u - 32));   // T14: math late
      if (u < 32)      feats(u & 3, nb);
      else if (u < 40) znorm(nb);
      else             gfcopy(u - 40, nb);
    }
    __syncthreads();
  }

  // ---- final epilogue: alpha, silu, LayerScale, residual ----
  float gbv[4], gmv[4];
  #pragma unroll
  for (int nt = 0; nt < 4; ++nt) {
    int col = wc * 64 + nt * 16 + fr;
    gbv[nt] = gbias[col]; gmv[nt] = gamma[col];
  }
  #pragma unroll
  for (int ai = 0; ai < 4; ++ai) {
    #pragma unroll
    for (int rr = 0; rr < 4; ++rr) {
      const long pix = pix0 + wr * 64 + ai * 16 + kq * 4 + rr;
      const f32x2 m2 = *(const f32x2*)(mu_rs + pix * 2);
      #pragma unroll
      for (int nt = 0; nt < 4; ++nt) {
        int col = wc * 64 + nt * 16 + fr;
        float xv = x[pix * 256 + col];
        float hh = (xv - m2[0]) * m2[1] * gsh[col] + bsh[col];
        u32 pw = gfp[ai][nt][rr >> 1];
        float gfv = bfu2f((u16)((rr & 1) ? (pw >> 16) : pw));
        float al = fsigmoid(acc[ai][nt][rr] + gbv[nt]);
        out[pix * 256 + col] = xv + (fsilu(hh) + al * gfv) * gmv[nt];
      }
    }
  }
}

extern "C" void kernel_launch(void* const* d_in, const int* in_sizes, int n_in,
                              void* d_out, int out_size, void* d_ws, size_t ws_size,
                              hipStream_t stream) {
  const float* x     = (const float*)d_in[0];
  const float* lng   = (const float*)d_in[1];
  const float* lnb   = (const float*)d_in[2];
  const float* pk    = (const float*)d_in[3];
  const float* pbias = (const float*)d_in[4];
  const float* gk    = (const float*)d_in[5];
  const float* gbias = (const float*)d_in[6];
  const float* gamma = (const float*)d_in[7];
  float* out = (float*)d_out;

  char* ws = (char*)d_ws;
  u16*   wsw     = (u16*)ws;                       // 786432 B
  float* mu_rs   = (float*)(ws + 786432);          // 589824 B
  float* partial = (float*)(ws + 1376256);         // 786432 B
  float* meang   = (float*)(ws + 2162688);         // 8256 B  (total ~2.07 MB)

  wconv<<<192, 256, 0, stream>>>(pk, gk, wsw);
  prep<<<768, 256, 0, stream>>>(x, lng, lnb, mu_rs, partial);
  ln_mean<<<8, 256, 0, stream>>>(partial, meang);
  fused<<<NPIX / MROW, 512, 0, stream>>>(x, lng, lnb, wsw, mu_rs,
                                         pbias, gbias, gamma, meang, out);
}

// Round 6
// 190.302 us; speedup vs baseline: 2.7950x; 2.7950x over previous
//
#include <hip/hip_runtime.h>
#include <hip/hip_bf16.h>

typedef unsigned short u16;
typedef unsigned int   u32;
typedef __attribute__((ext_vector_type(4))) float f32x4;
typedef __attribute__((ext_vector_type(4))) u32   u32x4;
typedef __attribute__((ext_vector_type(8))) short bf16x8;

#define HWPIX  9216
#define NPIX   73728
#define LN_EPS 1e-5f
#define MROW   64       // pixels per block
#define HSTR   264      // hn row stride (elems): 256 + 8 pad (incl. 2-ch wrap pad)
#define ASTR   40       // afg chunk row stride (elems): 32 + 8 pad

template<int N> struct IC { static constexpr int value = N; };

__device__ __forceinline__ u16 f2bf(float f){
  u32 u = __builtin_bit_cast(u32, f);
  u += 0x7fffu + ((u >> 16) & 1u);          // RTNE
  return (u16)(u >> 16);
}
__device__ __forceinline__ float lo2f(u32 w){ return __builtin_bit_cast(float, w << 16); }
__device__ __forceinline__ float hi2f(u32 w){ return __builtin_bit_cast(float, w & 0xffff0000u); }
__device__ __forceinline__ float bfu2f(u16 h){ return __builtin_bit_cast(float, (u32)h << 16); }
__device__ __forceinline__ float fsigmoid(float v){ return __fdividef(1.f, 1.f + __expf(-v)); }
__device__ __forceinline__ float fsilu(float v){ return __fdividef(v, 1.f + __expf(-v)); }

// ---------------- kernel 1: weight convert into staging-order swizzled layout ------
// wsw[t][S][0..7] (u16): chunk t (0..47), slot S (0..1023). Slot S maps to
// B-col n = (S>>9)*128 + ((S>>6)&7)*16 + ((S>>2)&15), phys k-slot p = S&3,
// content k-quarter kq = p ^ ((((S>>2)&15)>>1)&3)  (XOR bank swizzle).
__global__ __launch_bounds__(256) void wconv(const float* __restrict__ pk,
                                             const float* __restrict__ gk,
                                             u16* __restrict__ wsw)
{
  int gid = blockIdx.x * 256 + threadIdx.x;   // 49152 total = 192 blocks
  int t = gid >> 10, S = gid & 1023;
  int q = (S >> 2) & 15, pp = S & 3, w8 = (S >> 6) & 7, rb = S >> 9;
  int n  = rb * 128 + w8 * 16 + q;
  int kq = pp ^ ((q >> 1) & 3);
  const float* W; int k0;
  if (t < 32) { W = pk; k0 = t * 32 + kq * 8; }
  else        { W = gk; k0 = (t - 32) * 32 + kq * 8; }
  u32 ow[4];
  #pragma unroll
  for (int e = 0; e < 4; ++e) {
    float f0 = W[(size_t)(k0 + 2*e)     * 256 + n];
    float f1 = W[(size_t)(k0 + 2*e + 1) * 256 + n];
    ow[e] = (u32)f2bf(f0) | ((u32)f2bf(f1) << 16);
  }
  *(u32x4*)(wsw + (size_t)gid * 8) = (u32x4){ow[0], ow[1], ow[2], ow[3]};
}

// ---------------- kernel 2: per-(b,h) partial sums of h_norm over w ----------------
__global__ __launch_bounds__(256) void ln_partial(const float* __restrict__ x,
                                                  const float* __restrict__ g,
                                                  const float* __restrict__ bt,
                                                  float* __restrict__ partial) // [768][256]
{
  const int bh = blockIdx.x;
  const int tid = threadIdx.x;
  const int wv = tid >> 6, lane = tid & 63;
  const float* xrow = x + (size_t)bh * 96 * 256;
  __shared__ float red[4][256];

  f32x4 gv = *(const f32x4*)(g  + lane * 4);
  f32x4 bv = *(const f32x4*)(bt + lane * 4);
  f32x4 acc = {0.f, 0.f, 0.f, 0.f};

  for (int w = wv; w < 96; w += 4) {
    f32x4 v = *(const f32x4*)(xrow + w * 256 + lane * 4);
    float s  = v[0] + v[1] + v[2] + v[3];
    float s2 = v[0]*v[0] + v[1]*v[1] + v[2]*v[2] + v[3]*v[3];
    #pragma unroll
    for (int m = 1; m < 64; m <<= 1) { s += __shfl_xor(s, m); s2 += __shfl_xor(s2, m); }
    float mu  = s * (1.f / 256.f);
    float var = s2 * (1.f / 256.f) - mu * mu;
    float rs  = rsqrtf(var + LN_EPS);
    #pragma unroll
    for (int j = 0; j < 4; ++j) acc[j] += (v[j] - mu) * rs * gv[j] + bv[j];
  }
  *(f32x4*)(&red[wv][lane * 4]) = acc;
  __syncthreads();
  float s = red[0][tid] + red[1][tid] + red[2][tid] + red[3][tid];
  partial[(size_t)bh * 256 + tid] = s;
}

// ---------------- kernel 3: reduce rows -> spatial mean [8][258] (wrap-padded) -----
__global__ __launch_bounds__(256) void ln_mean(const float* __restrict__ partial,
                                               float* __restrict__ mean)
{
  int b = blockIdx.x, c = threadIdx.x;
  float s = 0.f;
  for (int h = 0; h < 96; ++h) s += partial[((size_t)b * 96 + h) * 256 + c];
  float m = s * (1.f / 9216.f);
  mean[b * 258 + c] = m;
  if (c < 2) mean[b * 258 + 256 + c] = m;
}

// ---------------- kernel 4: fused main ---------------------------------------------
// 64 pixels/block, 512 threads (8 waves 2x4, wave tile 32x64). h_norm persists in LDS
// (hn); Clifford feats built per 32-K chunk into dbuf afg from hn + msh. B staged
// global->REG (early) -> ds_write (late): plain-HIP deps only, no LDS-DMA semantics.
// 77.8KB LDS -> 2 blk/CU.
__global__ __launch_bounds__(512, 4) void fused(
    const float* __restrict__ x,
    const float* __restrict__ lng, const float* __restrict__ lnb,
    const u16*  __restrict__ wsw,
    const float* __restrict__ pbias, const float* __restrict__ gbias,
    const float* __restrict__ gamma, const float* __restrict__ meang,
    float* __restrict__ out)
{
  __shared__ u16 hn[MROW * HSTR];       // 33792 B  h_norm bf16 (persists)
  __shared__ u16 afg[2][MROW * ASTR];   // 10240 B  A chunk dbuf
  __shared__ u16 Bl [2][8192];          // 32768 B  B chunk dbuf
  __shared__ float msh[258];            //  1032 B  spatial mean (wrap-padded)

  const int tid  = threadIdx.x;
  const long pix0 = (long)blockIdx.x * MROW;
  const int bat  = (int)(pix0 / HWPIX);      // 9216 % 64 == 0

  if (tid < 258) msh[tid] = meang[bat * 258 + tid];

  const int wave = tid >> 6, lane = tid & 63;
  const int wr = wave & 1, wc = wave >> 1;       // 2x4 wave grid
  const int fr = lane & 15, kq = lane >> 4;
  const int bswz = (kq ^ ((fr >> 1) & 3)) * 8;
  const int br = tid >> 3, bo = (tid & 7) * 4;   // feats build: row, 4-ch slice

  f32x4 acc[2][4];
  #pragma unroll
  for (int i = 0; i < 2; ++i)
    #pragma unroll
    for (int j = 0; j < 4; ++j) acc[i][j] = (f32x4){0.f, 0.f, 0.f, 0.f};
  u32 gfp[2][4][2];
  float pbv[4];
  #pragma unroll
  for (int nt = 0; nt < 4; ++nt) pbv[nt] = pbias[wc * 64 + nt * 16 + fr];

  // ---- B staging: global -> regs (issue early), regs -> LDS (write late) ----
  u32x4 breg0, breg1;
  auto loadB = [&](int u) {
    const u16* src = wsw + (size_t)u * 8192 + tid * 8;
    breg0 = *(const u32x4*)(src);
    breg1 = *(const u32x4*)(src + 4096);
  };
  auto writeB = [&](int buf) {
    *(u32x4*)(&Bl[buf][tid * 8])        = breg0;
    *(u32x4*)(&Bl[buf][tid * 8 + 4096]) = breg1;
  };

  loadB(0);

  // ---- preproc: LN -> hn (8 lanes/pixel, 32 ch each) ----
  {
    const int p = tid >> 3, o = tid & 7;
    const float* xp = x + (pix0 + p) * 256 + o * 32;
    f32x4 v[8];
    float s = 0.f, s2 = 0.f;
    #pragma unroll
    for (int i = 0; i < 8; ++i) {
      v[i] = *(const f32x4*)(xp + i * 4);
      #pragma unroll
      for (int j = 0; j < 4; ++j) { s += v[i][j]; s2 += v[i][j] * v[i][j]; }
    }
    s += __shfl_xor(s, 1); s2 += __shfl_xor(s2, 1);
    s += __shfl_xor(s, 2); s2 += __shfl_xor(s2, 2);
    s += __shfl_xor(s, 4); s2 += __shfl_xor(s2, 4);
    float mu  = s * (1.f / 256.f);
    float var = s2 * (1.f / 256.f) - mu * mu;
    float rs  = rsqrtf(var + LN_EPS);

    const float* gp = lng + o * 32;
    const float* bp = lnb + o * 32;
    u16* zd = hn + p * HSTR + o * 32;
    u32 pad_d = 0;
    #pragma unroll
    for (int i = 0; i < 8; ++i) {
      f32x4 gg = *(const f32x4*)(gp + i * 4);
      f32x4 bb = *(const f32x4*)(bp + i * 4);
      float h0 = (v[i][0] - mu) * rs * gg[0] + bb[0];
      float h1 = (v[i][1] - mu) * rs * gg[1] + bb[1];
      float h2 = (v[i][2] - mu) * rs * gg[2] + bb[2];
      float h3 = (v[i][3] - mu) * rs * gg[3] + bb[3];
      u32 d0 = (u32)f2bf(h0) | ((u32)f2bf(h1) << 16);
      u32 d1 = (u32)f2bf(h2) | ((u32)f2bf(h3) << 16);
      *(u32*)(zd + i * 4)     = d0;
      *(u32*)(zd + i * 4 + 2) = d1;
      if (i == 0) pad_d = d0;
    }
    if (o == 0) *(u32*)(hn + p * HSTR + 256) = pad_d;   // wrap pad ch[256,257]
  }

  // feats: chunk u (u<32) -> comp = u>>3, window w = u&7. Reads hn window from LDS
  // (runtime LDS addresses ok; NO runtime-indexed register arrays).
  auto feats = [&](int u, int buf) {
    const int comp = u >> 3;
    const bool s1 = (comp >> 1) == 0;          // shift 1 vs 2
    const bool isdot = (comp & 1) == 0;
    const int cc = (u & 7) * 32 + bo;
    const u16* zp = hn + br * HSTR + cc;
    u32 a0 = *(const u32*)(zp);
    u32 a1 = *(const u32*)(zp + 2);
    u32 a2 = *(const u32*)(zp + 4);
    float h0 = lo2f(a0), h1 = hi2f(a0), h2 = lo2f(a1);
    float h3 = hi2f(a1), h4 = lo2f(a2), h5 = hi2f(a2);
    float m0 = msh[cc],     m1 = msh[cc + 1], m2 = msh[cc + 2];
    float m3 = msh[cc + 3], m4 = msh[cc + 4], m5 = msh[cc + 5];
    float zs0 = s1 ? h1 : h2,  ms0 = s1 ? m1 : m2;
    float zs1 = s1 ? h2 : h3,  ms1 = s1 ? m2 : m3;
    float zs2 = s1 ? h3 : h4,  ms2 = s1 ? m3 : m4;
    float zs3 = s1 ? h4 : h5,  ms3 = s1 ? m4 : m5;
    float r0, r1, r2, r3;
    if (isdot) {
      r0 = fsilu(h0 * (zs0 - ms0));
      r1 = fsilu(h1 * (zs1 - ms1));
      r2 = fsilu(h2 * (zs2 - ms2));
      r3 = fsilu(h3 * (zs3 - ms3));
    } else {
      r0 = m0 * zs0 - ms0 * h0;
      r1 = m1 * zs1 - ms1 * h1;
      r2 = m2 * zs2 - ms2 * h2;
      r3 = m3 * zs3 - ms3 * h3;
    }
    u32 w0 = (u32)f2bf(r0) | ((u32)f2bf(r1) << 16);
    u32 w1 = (u32)f2bf(r2) | ((u32)f2bf(r3) << 16);
    *(u32*)(&afg[buf][br * ASTR + bo])     = w0;
    *(u32*)(&afg[buf][br * ASTR + bo + 2]) = w1;
  };

  // gfcopy: g_feat chunk (u-40) from packed regs into afg (compile-time nt parity)
  auto gfcopy = [&](auto PAR, int cghi, int buf) {
    constexpr int par = decltype(PAR)::value;
    if (wc == cghi) {
      #pragma unroll
      for (int v = 0; v < 2; ++v) {
        #pragma unroll
        for (int ai = 0; ai < 2; ++ai)
          #pragma unroll
          for (int rp = 0; rp < 2; ++rp) {
            u32 pw = gfp[ai][par * 2 + v][rp];
            int row0 = wr * 32 + ai * 16 + kq * 4 + rp * 2;
            afg[buf][row0 * ASTR + v * 16 + fr]       = (u16)pw;
            afg[buf][(row0 + 1) * ASTR + v * 16 + fr] = (u16)(pw >> 16);
          }
      }
    }
  };

  auto domfma = [&](const u16* abase, int astr, int buf) {
    bf16x8 av0 = *(const bf16x8*)(abase);
    bf16x8 av1 = *(const bf16x8*)(abase + 16 * astr);
    const u16* bp = &Bl[buf][wc * 2048 + fr * 32 + bswz];
    #pragma unroll
    for (int nt = 0; nt < 4; ++nt) {
      bf16x8 bv = *(const bf16x8*)(bp + nt * 512);
      acc[0][nt] = __builtin_amdgcn_mfma_f32_16x16x32_bf16(av0, bv, acc[0][nt], 0, 0, 0);
      acc[1][nt] = __builtin_amdgcn_mfma_f32_16x16x32_bf16(av1, bv, acc[1][nt], 0, 0, 0);
    }
  };

  __syncthreads();                    // hn, msh visible
  writeB(0);                          // Bl[0] from prologue regs
  feats(0, 0);
  __syncthreads();                    // Bl[0], afg[0] visible

  for (int t = 0; t < 48; ++t) {
    const int cb = t & 1, nb = cb ^ 1;
    const int u = t + 1;
    if (u < 48) loadB(u);                           // issue early (T14)
    if (u < 32) {
      feats(u, nb);
    } else if (u >= 40 && u < 48) {
      const int cg = u - 40;
      if (cg & 1) gfcopy(IC<1>{}, cg >> 1, nb);
      else        gfcopy(IC<0>{}, cg >> 1, nb);
    }
    if (t < 32)      domfma(&afg[cb][(wr * 32 + fr) * ASTR + kq * 8], ASTR, cb);
    else if (t < 40) domfma(&hn[(wr * 32 + fr) * HSTR + (t - 32) * 32 + kq * 8], HSTR, cb);
    else             domfma(&afg[cb][(wr * 32 + fr) * ASTR + kq * 8], ASTR, cb);
    if (t == 31) {                    // fold GEMM1 -> packed bf16 g_feat regs
      #pragma unroll
      for (int nt = 0; nt < 4; ++nt)
        #pragma unroll
        for (int ai = 0; ai < 2; ++ai) {
          f32x4 a = acc[ai][nt];
          gfp[ai][nt][0] = (u32)f2bf(a[0] + pbv[nt]) | ((u32)f2bf(a[1] + pbv[nt]) << 16);
          gfp[ai][nt][1] = (u32)f2bf(a[2] + pbv[nt]) | ((u32)f2bf(a[3] + pbv[nt]) << 16);
          acc[ai][nt] = (f32x4){0.f, 0.f, 0.f, 0.f};
        }
    }
    if (u < 48) writeB(nb);           // regs -> LDS (vmcnt wait auto-inserted here)
    __syncthreads();
  }

  // ---- final epilogue: alpha, silu, LayerScale, residual ----
  float gbv[4], gmv[4];
  #pragma unroll
  for (int nt = 0; nt < 4; ++nt) {
    int col = wc * 64 + nt * 16 + fr;
    gbv[nt] = gbias[col]; gmv[nt] = gamma[col];
  }
  #pragma unroll
  for (int ai = 0; ai < 2; ++ai)
    #pragma unroll
    for (int rr = 0; rr < 4; ++rr) {
      const int row = wr * 32 + ai * 16 + kq * 4 + rr;
      const long pix = pix0 + row;
      #pragma unroll
      for (int nt = 0; nt < 4; ++nt) {
        int col = wc * 64 + nt * 16 + fr;
        float xv = x[pix * 256 + col];
        float hh = bfu2f(hn[row * HSTR + col]);
        u32 pw = gfp[ai][nt][rr >> 1];
        float gfv = bfu2f((u16)((rr & 1) ? (pw >> 16) : pw));
        float al = fsigmoid(acc[ai][nt][rr] + gbv[nt]);
        out[pix * 256 + col] = xv + (fsilu(hh) + al * gfv) * gmv[nt];
      }
    }
}

extern "C" void kernel_launch(void* const* d_in, const int* in_sizes, int n_in,
                              void* d_out, int out_size, void* d_ws, size_t ws_size,
                              hipStream_t stream) {
  const float* x     = (const float*)d_in[0];
  const float* lng   = (const float*)d_in[1];
  const float* lnb   = (const float*)d_in[2];
  const float* pk    = (const float*)d_in[3];
  const float* pbias = (const float*)d_in[4];
  const float* gk    = (const float*)d_in[5];
  const float* gbias = (const float*)d_in[6];
  const float* gamma = (const float*)d_in[7];
  float* out = (float*)d_out;

  char* ws = (char*)d_ws;
  u16*   wsw     = (u16*)ws;                       // 786432 B
  float* partial = (float*)(ws + 786432);          // 786432 B
  float* meang   = (float*)(ws + 1572864);         // 8256 B  (total ~1.58 MB)

  wconv<<<192, 256, 0, stream>>>(pk, gk, wsw);
  ln_partial<<<768, 256, 0, stream>>>(x, lng, lnb, partial);
  ln_mean<<<8, 256, 0, stream>>>(partial, meang);
  fused<<<NPIX / MROW, 512, 0, stream>>>(x, lng, lnb, wsw,
                                         pbias, gbias, gamma, meang, out);
}

// Round 7
// 165.673 us; speedup vs baseline: 3.2104x; 1.1487x over previous
//
#include <hip/hip_runtime.h>
#include <hip/hip_bf16.h>

typedef unsigned short u16;
typedef unsigned int   u32;
typedef __attribute__((ext_vector_type(4))) float f32x4;
typedef __attribute__((ext_vector_type(4))) u32   u32x4;
typedef __attribute__((ext_vector_type(8))) short bf16x8;

#define HWPIX  9216
#define NPIX   73728
#define LN_EPS 1e-5f
#define MROW   64       // pixels per block
#define HSTR   264      // hn row stride (elems): 256 + 8 pad (incl. 2-ch wrap pad)
#define ASTR   40       // afg chunk row stride (elems): 32 + 8 pad

template<int N> struct IC { static constexpr int value = N; };

__device__ __forceinline__ u16 f2bf(float f){
  u32 u = __builtin_bit_cast(u32, f);
  u += 0x7fffu + ((u >> 16) & 1u);          // RTNE
  return (u16)(u >> 16);
}
__device__ __forceinline__ u32 pkbf(float lo, float hi){   // 1 inst: dst.lo=bf16(lo), dst.hi=bf16(hi)
  u32 d;
  asm("v_cvt_pk_bf16_f32 %0, %1, %2" : "=v"(d) : "v"(lo), "v"(hi));
  return d;
}
__device__ __forceinline__ float lo2f(u32 w){ return __builtin_bit_cast(float, w << 16); }
__device__ __forceinline__ float hi2f(u32 w){ return __builtin_bit_cast(float, w & 0xffff0000u); }
__device__ __forceinline__ float bfu2f(u16 h){ return __builtin_bit_cast(float, (u32)h << 16); }
__device__ __forceinline__ float fsigmoid(float v){ return __fdividef(1.f, 1.f + __expf(-v)); }
__device__ __forceinline__ float fsilu(float v){ return __fdividef(v, 1.f + __expf(-v)); }

// ---------------- kernel 1: weight convert (dot + gate) into staging layout --------
// chunk t, slot S: n = (S>>9)*128 + ((S>>6)&7)*16 + ((S>>2)&15), pp = S&3,
// content k-quarter kq = pp ^ ((((S>>2)&15)>>1)&3)  (XOR bank swizzle).
__global__ __launch_bounds__(256) void wconv(const float* __restrict__ pk,
                                             const float* __restrict__ gk,
                                             u16* __restrict__ wsdot,   // 16 chunks
                                             u16* __restrict__ wsgate)  // 16 chunks
{
  int gid = blockIdx.x * 256 + threadIdx.x;   // 32768 = 128 blocks
  int t = gid >> 10, S = gid & 1023;
  int q = (S >> 2) & 15, pp = S & 3, w8 = (S >> 6) & 7, rb = S >> 9;
  int n  = rb * 128 + w8 * 16 + q;
  int kq = pp ^ ((q >> 1) & 3);
  const float* W; int k0; u16* dst;
  if (t < 8)       { W = pk; k0 =       t      * 32 + kq * 8; dst = wsdot  + (size_t)t * 8192; }
  else if (t < 16) { W = pk; k0 = 512 + (t-8)  * 32 + kq * 8; dst = wsdot  + (size_t)t * 8192; }
  else             { W = gk; k0 =       (t-16) * 32 + kq * 8; dst = wsgate + (size_t)(t-16) * 8192; }
  u32 ow[4];
  #pragma unroll
  for (int e = 0; e < 4; ++e) {
    float f0 = W[(size_t)(k0 + 2*e)     * 256 + n];
    float f1 = W[(size_t)(k0 + 2*e + 1) * 256 + n];
    ow[e] = (u32)f2bf(f0) | ((u32)f2bf(f1) << 16);
  }
  *(u32x4*)(dst + (size_t)S * 8) = (u32x4){ow[0], ow[1], ow[2], ow[3]};
}

// ---------------- kernel 2: per-(b,h) partial sums of h_norm over w ----------------
__global__ __launch_bounds__(256) void ln_partial(const float* __restrict__ x,
                                                  const float* __restrict__ g,
                                                  const float* __restrict__ bt,
                                                  float* __restrict__ partial) // [768][256]
{
  const int bh = blockIdx.x;
  const int tid = threadIdx.x;
  const int wv = tid >> 6, lane = tid & 63;
  const float* xrow = x + (size_t)bh * 96 * 256;
  __shared__ float red[4][256];

  f32x4 gv = *(const f32x4*)(g  + lane * 4);
  f32x4 bv = *(const f32x4*)(bt + lane * 4);
  f32x4 acc = {0.f, 0.f, 0.f, 0.f};

  for (int w = wv; w < 96; w += 4) {
    f32x4 v = *(const f32x4*)(xrow + w * 256 + lane * 4);
    float s  = v[0] + v[1] + v[2] + v[3];
    float s2 = v[0]*v[0] + v[1]*v[1] + v[2]*v[2] + v[3]*v[3];
    #pragma unroll
    for (int m = 1; m < 64; m <<= 1) { s += __shfl_xor(s, m); s2 += __shfl_xor(s2, m); }
    float mu  = s * (1.f / 256.f);
    float var = s2 * (1.f / 256.f) - mu * mu;
    float rs  = rsqrtf(var + LN_EPS);
    #pragma unroll
    for (int j = 0; j < 4; ++j) acc[j] += (v[j] - mu) * rs * gv[j] + bv[j];
  }
  *(f32x4*)(&red[wv][lane * 4]) = acc;
  __syncthreads();
  float s = red[0][tid] + red[1][tid] + red[2][tid] + red[3][tid];
  partial[(size_t)bh * 256 + tid] = s;
}

// ---------------- kernel 3: reduce rows -> spatial mean [8][258] (wrap-padded) -----
__global__ __launch_bounds__(256) void ln_mean(const float* __restrict__ partial,
                                               float* __restrict__ mean)
{
  int b = blockIdx.x, c = threadIdx.x;
  float s = 0.f;
  for (int h = 0; h < 96; ++h) s += partial[((size_t)b * 96 + h) * 256 + c];
  float m = s * (1.f / 9216.f);
  mean[b * 258 + c] = m;
  if (c < 2) mean[b * 258 + 256 + c] = m;
}

// ---------------- kernel 4: fold wedge into per-batch weights ----------------------
// wedge_s[c] = m[c]h[c+s] - m[c+s]h[c]  (linear in h) =>
// W'_b[c,n] = sum_s m[c-s]*Ww_s[c-s,n] - m[c+s]*Ww_s[c,n];  Ww_1 = pk rows 256..511,
// Ww_2 = pk rows 768..1023. Output in staging layout: 64 chunks = [b][j].
__global__ __launch_bounds__(256) void wfold(const float* __restrict__ pk,
                                             const float* __restrict__ meang,
                                             u16* __restrict__ wsW)
{
  __shared__ float msh[256];
  int gid = blockIdx.x * 256 + threadIdx.x;   // 65536 = 256 blocks
  int chunk = gid >> 10;                      // 0..63 (uniform per block)
  int b = chunk >> 3, j = chunk & 7;
  msh[threadIdx.x] = meang[b * 258 + threadIdx.x];
  __syncthreads();
  int S = gid & 1023;
  int q = (S >> 2) & 15, pp = S & 3, w8 = (S >> 6) & 7, rb = S >> 9;
  int n  = rb * 128 + w8 * 16 + q;
  int kq = pp ^ ((q >> 1) & 3);
  u32 ow[4];
  #pragma unroll
  for (int e = 0; e < 4; ++e) {
    float r[2];
    #pragma unroll
    for (int hh = 0; hh < 2; ++hh) {
      int c = j * 32 + kq * 8 + 2 * e + hh;
      int cm1 = (c + 255) & 255, cm2 = (c + 254) & 255;
      int cp1 = (c + 1) & 255,   cp2 = (c + 2) & 255;
      r[hh] = msh[cm1] * pk[(size_t)(256 + cm1) * 256 + n]
            - msh[cp1] * pk[(size_t)(256 + c)   * 256 + n]
            + msh[cm2] * pk[(size_t)(768 + cm2) * 256 + n]
            - msh[cp2] * pk[(size_t)(768 + c)   * 256 + n];
    }
    ow[e] = (u32)f2bf(r[0]) | ((u32)f2bf(r[1]) << 16);
  }
  *(u32x4*)(wsW + (size_t)chunk * 8192 + (size_t)S * 8) = (u32x4){ow[0], ow[1], ow[2], ow[3]};
}

// ---------------- kernel 5: fused main ---------------------------------------------
// 64 pixels/block, 512 threads (8 waves 2x4, wave tile 32x64). 40 K-chunks in 5
// compile-time segments: [dot s=1 | dot s=2 | h@W'(folded wedge) | gate-h | gate-gf].
// Segments 2,3 read A straight from hn (no build). Fully unrolled -> all flags,
// windows, parities are compile-time (no if-conversion, minimal address VALU).
__global__ __launch_bounds__(512, 4) void fused(
    const float* __restrict__ x,
    const float* __restrict__ lng, const float* __restrict__ lnb,
    const u16* __restrict__ wsdot, const u16* __restrict__ wsW,
    const u16* __restrict__ wsgate,
    const float* __restrict__ pbias, const float* __restrict__ gbias,
    const float* __restrict__ gamma, const float* __restrict__ meang,
    float* __restrict__ out)
{
  __shared__ u16 hn[MROW * HSTR];       // 33792 B  h_norm bf16 (persists)
  __shared__ u16 afg[2][MROW * ASTR];   // 10240 B  A chunk dbuf (segs 0,1,4)
  __shared__ u16 Bl [2][8192];          // 32768 B  B chunk dbuf
  __shared__ float msh[258];            //  1032 B  spatial mean (wrap-padded)

  const int tid  = threadIdx.x;
  const long pix0 = (long)blockIdx.x * MROW;
  const int bat  = (int)(pix0 / HWPIX);      // 9216 % 64 == 0

  if (tid < 258) msh[tid] = meang[bat * 258 + tid];

  const int wave = tid >> 6, lane = tid & 63;
  const int wr = wave & 1, wc = wave >> 1;       // 2x4 wave grid
  const int fr = lane & 15, kq = lane >> 4;
  const int bswz = (kq ^ ((fr >> 1) & 3)) * 8;
  const int br = tid >> 3, bo = (tid & 7) * 4;   // feats build: row, 4-ch slice

  f32x4 acc[2][4];
  #pragma unroll
  for (int i = 0; i < 2; ++i)
    #pragma unroll
    for (int j = 0; j < 4; ++j) acc[i][j] = (f32x4){0.f, 0.f, 0.f, 0.f};
  u32 gfp[2][4][2];
  float pbv[4];
  #pragma unroll
  for (int nt = 0; nt < 4; ++nt) pbv[nt] = pbias[wc * 64 + nt * 16 + fr];

  // ---- B staging: global -> regs (issue early), regs -> LDS (write late) ----
  u32x4 breg0, breg1;
  auto sgptr = [&](auto SG) -> const u16* {
    constexpr int sg = decltype(SG)::value;
    if constexpr      (sg == 0) return wsdot;
    else if constexpr (sg == 1) return wsdot + 8 * 8192;
    else if constexpr (sg == 2) return wsW + (size_t)bat * 65536;
    else if constexpr (sg == 3) return wsgate;
    else                        return wsgate + 8 * 8192;
  };
  auto loadB = [&](auto SG, int jn) {
    const u16* src = sgptr(SG) + (size_t)jn * 8192 + tid * 8;
    breg0 = *(const u32x4*)(src);
    breg1 = *(const u32x4*)(src + 4096);
  };
  auto writeB = [&](int buf) {
    *(u32x4*)(&Bl[buf][tid * 8])        = breg0;
    *(u32x4*)(&Bl[buf][tid * 8 + 4096]) = breg1;
  };

  loadB(IC<0>{}, 0);

  // ---- preproc: LN -> hn (8 lanes/pixel, 32 ch each) ----
  {
    const int p = tid >> 3, o = tid & 7;
    const float* xp = x + (pix0 + p) * 256 + o * 32;
    f32x4 v[8];
    float s = 0.f, s2 = 0.f;
    #pragma unroll
    for (int i = 0; i < 8; ++i) {
      v[i] = *(const f32x4*)(xp + i * 4);
      #pragma unroll
      for (int j = 0; j < 4; ++j) { s += v[i][j]; s2 += v[i][j] * v[i][j]; }
    }
    s += __shfl_xor(s, 1); s2 += __shfl_xor(s2, 1);
    s += __shfl_xor(s, 2); s2 += __shfl_xor(s2, 2);
    s += __shfl_xor(s, 4); s2 += __shfl_xor(s2, 4);
    float mu  = s * (1.f / 256.f);
    float var = s2 * (1.f / 256.f) - mu * mu;
    float rs  = rsqrtf(var + LN_EPS);

    const float* gp = lng + o * 32;
    const float* bp = lnb + o * 32;
    u16* zd = hn + p * HSTR + o * 32;
    u32 pad_d = 0;
    #pragma unroll
    for (int i = 0; i < 8; ++i) {
      f32x4 gg = *(const f32x4*)(gp + i * 4);
      f32x4 bb = *(const f32x4*)(bp + i * 4);
      float h0 = (v[i][0] - mu) * rs * gg[0] + bb[0];
      float h1 = (v[i][1] - mu) * rs * gg[1] + bb[1];
      float h2 = (v[i][2] - mu) * rs * gg[2] + bb[2];
      float h3 = (v[i][3] - mu) * rs * gg[3] + bb[3];
      u32 d0 = pkbf(h0, h1);
      u32 d1 = pkbf(h2, h3);
      *(u32*)(zd + i * 4)     = d0;
      *(u32*)(zd + i * 4 + 2) = d1;
      if (i == 0) pad_d = d0;
    }
    if (o == 0) *(u32*)(hn + p * HSTR + 256) = pad_d;   // wrap pad ch[256,257]
  }

  // dot feats for shift s (compile-time), window w (compile-time) -> afg[buf]
  auto featsD = [&](auto SC, int w, int buf) {
    constexpr int s = decltype(SC)::value;
    const int cc = w * 32 + bo;
    const u16* zp = hn + br * HSTR + cc;
    u32 a0 = *(const u32*)(zp);
    u32 a1 = *(const u32*)(zp + 2);
    u32 a2 = *(const u32*)(zp + 4);
    float h0 = lo2f(a0), h1 = hi2f(a0), h2 = lo2f(a1);
    float h3 = hi2f(a1), h4 = lo2f(a2), h5 = hi2f(a2);
    float m0 = msh[cc + s], m1 = msh[cc + s + 1];
    float m2 = msh[cc + s + 2], m3 = msh[cc + s + 3];
    float t0, t1, t2, t3;
    if constexpr (s == 1) { t0 = h1; t1 = h2; t2 = h3; t3 = h4; }
    else                  { t0 = h2; t1 = h3; t2 = h4; t3 = h5; }
    float r0 = fsilu(h0 * (t0 - m0));
    float r1 = fsilu(h1 * (t1 - m1));
    float r2 = fsilu(h2 * (t2 - m2));
    float r3 = fsilu(h3 * (t3 - m3));
    *(u32*)(&afg[buf][br * ASTR + bo])     = pkbf(r0, r1);
    *(u32*)(&afg[buf][br * ASTR + bo + 2]) = pkbf(r2, r3);
  };

  // g_feat chunk cg (compile-time) from packed regs into afg
  auto gfcopy = [&](auto CGC, int buf) {
    constexpr int cg = decltype(CGC)::value;
    constexpr int par = cg & 1;
    if (wc == (cg >> 1)) {
      #pragma unroll
      for (int v = 0; v < 2; ++v) {
        #pragma unroll
        for (int ai = 0; ai < 2; ++ai)
          #pragma unroll
          for (int rp = 0; rp < 2; ++rp) {
            u32 pw = gfp[ai][par * 2 + v][rp];
            int row0 = wr * 32 + ai * 16 + kq * 4 + rp * 2;
            afg[buf][row0 * ASTR + v * 16 + fr]       = (u16)pw;
            afg[buf][(row0 + 1) * ASTR + v * 16 + fr] = (u16)(pw >> 16);
          }
      }
    }
  };

  auto domfma = [&](const u16* abase, int astr, int buf) {
    bf16x8 av0 = *(const bf16x8*)(abase);
    bf16x8 av1 = *(const bf16x8*)(abase + 16 * astr);
    const u16* bp = &Bl[buf][wc * 2048 + fr * 32 + bswz];
    #pragma unroll
    for (int nt = 0; nt < 4; ++nt) {
      bf16x8 bv = *(const bf16x8*)(bp + nt * 512);
      acc[0][nt] = __builtin_amdgcn_mfma_f32_16x16x32_bf16(av0, bv, acc[0][nt], 0, 0, 0);
      acc[1][nt] = __builtin_amdgcn_mfma_f32_16x16x32_bf16(av1, bv, acc[1][nt], 0, 0, 0);
    }
  };

  __syncthreads();                    // hn, msh visible
  writeB(0);                          // Bl[0] from prologue regs
  featsD(IC<1>{}, 0, 0);              // afg[0] = dot s=1 window 0
  __syncthreads();                    // Bl[0], afg[0] visible

  auto stepfn = [&](auto SEGC, auto JC) {
    constexpr int SEG = decltype(SEGC)::value;
    constexpr int j   = decltype(JC)::value;
    constexpr int t   = SEG * 8 + j;
    constexpr int cb  = t & 1, nb = cb ^ 1;
    constexpr int u   = t + 1;
    constexpr int useg = (j == 7) ? SEG + 1 : SEG;
    constexpr int uj   = u & 7;
    if constexpr (u < 40) loadB(IC<useg>{}, uj);          // issue early (T14)
    if constexpr      (useg == 0) featsD(IC<1>{}, uj, nb);
    else if constexpr (useg == 1) featsD(IC<2>{}, uj, nb);
    else if constexpr (useg == 4 && u < 40) gfcopy(IC<u - 32>{}, nb);
    if constexpr (SEG == 0 || SEG == 1 || SEG == 4)
      domfma(&afg[cb][(wr * 32 + fr) * ASTR + kq * 8], ASTR, cb);
    else
      domfma(&hn[(wr * 32 + fr) * HSTR + j * 32 + kq * 8], HSTR, cb);
    if constexpr (t == 23) {          // end of GEMM1: fold to packed bf16 g_feat
      #pragma unroll
      for (int nt = 0; nt < 4; ++nt)
        #pragma unroll
        for (int ai = 0; ai < 2; ++ai) {
          f32x4 a = acc[ai][nt];
          gfp[ai][nt][0] = pkbf(a[0] + pbv[nt], a[1] + pbv[nt]);
          gfp[ai][nt][1] = pkbf(a[2] + pbv[nt], a[3] + pbv[nt]);
          acc[ai][nt] = (f32x4){0.f, 0.f, 0.f, 0.f};
        }
    }
    if constexpr (u < 40) writeB(nb); // regs -> LDS (vmcnt wait auto-inserted)
    __syncthreads();
  };
  auto runseg = [&](auto SEGC) {
    stepfn(SEGC, IC<0>{}); stepfn(SEGC, IC<1>{});
    stepfn(SEGC, IC<2>{}); stepfn(SEGC, IC<3>{});
    stepfn(SEGC, IC<4>{}); stepfn(SEGC, IC<5>{});
    stepfn(SEGC, IC<6>{}); stepfn(SEGC, IC<7>{});
  };
  runseg(IC<0>{}); runseg(IC<1>{}); runseg(IC<2>{});
  runseg(IC<3>{}); runseg(IC<4>{});

  // ---- final epilogue: alpha, silu, LayerScale, residual ----
  float gbv[4], gmv[4];
  #pragma unroll
  for (int nt = 0; nt < 4; ++nt) {
    int col = wc * 64 + nt * 16 + fr;
    gbv[nt] = gbias[col]; gmv[nt] = gamma[col];
  }
  #pragma unroll
  for (int ai = 0; ai < 2; ++ai)
    #pragma unroll
    for (int rr = 0; rr < 4; ++rr) {
      const int row = wr * 32 + ai * 16 + kq * 4 + rr;
      const long pix = pix0 + row;
      #pragma unroll
      for (int nt = 0; nt < 4; ++nt) {
        int col = wc * 64 + nt * 16 + fr;
        float xv = x[pix * 256 + col];
        float hh = bfu2f(hn[row * HSTR + col]);
        u32 pw = gfp[ai][nt][rr >> 1];
        float gfv = bfu2f((u16)((rr & 1) ? (pw >> 16) : pw));
        float al = fsigmoid(acc[ai][nt][rr] + gbv[nt]);
        out[pix * 256 + col] = xv + (fsilu(hh) + al * gfv) * gmv[nt];
      }
    }
}

extern "C" void kernel_launch(void* const* d_in, const int* in_sizes, int n_in,
                              void* d_out, int out_size, void* d_ws, size_t ws_size,
                              hipStream_t stream) {
  const float* x     = (const float*)d_in[0];
  const float* lng   = (const float*)d_in[1];
  const float* lnb   = (const float*)d_in[2];
  const float* pk    = (const float*)d_in[3];
  const float* pbias = (const float*)d_in[4];
  const float* gk    = (const float*)d_in[5];
  const float* gbias = (const float*)d_in[6];
  const float* gamma = (const float*)d_in[7];
  float* out = (float*)d_out;

  char* ws = (char*)d_ws;
  u16*   wsdot   = (u16*)ws;                       // 262144 B (16 chunks)
  u16*   wsgate  = (u16*)(ws + 262144);            // 262144 B (16 chunks)
  float* meang   = (float*)(ws + 524288);          // 8256 B
  u16*   wsW     = (u16*)(ws + 532544);            // 1048576 B (64 chunks, per-batch W')
  float* partial = (float*)(ws + 532544);          // 786432 B — dead before wfold writes W'
  // total 1,581,120 B (== round-6 footprint)

  wconv<<<128, 256, 0, stream>>>(pk, gk, wsdot, wsgate);
  ln_partial<<<768, 256, 0, stream>>>(x, lng, lnb, partial);
  ln_mean<<<8, 256, 0, stream>>>(partial, meang);
  wfold<<<256, 256, 0, stream>>>(pk, meang, wsW);
  fused<<<NPIX / MROW, 512, 0, stream>>>(x, lng, lnb, wsdot, wsW, wsgate,
                                         pbias, gbias, gamma, meang, out);
}

// Round 8
// 158.544 us; speedup vs baseline: 3.3548x; 1.0450x over previous
//
#include <hip/hip_runtime.h>
#include <hip/hip_bf16.h>

typedef unsigned short u16;
typedef unsigned int   u32;
typedef __attribute__((ext_vector_type(4))) float f32x4;
typedef __attribute__((ext_vector_type(4))) u32   u32x4;
typedef __attribute__((ext_vector_type(8))) short bf16x8;

#define HWPIX  9216
#define NPIX   73728
#define LN_EPS 1e-5f
#define MROW   64       // pixels per block
#define HSTR   264      // hn row stride (elems): 256 + 8 pad (incl. 2-ch wrap pad)
#define ASTR   40       // afg chunk row stride (elems): 32 + 8 pad

template<int N> struct IC { static constexpr int value = N; };

__device__ __forceinline__ u16 f2bf(float f){
  u32 u = __builtin_bit_cast(u32, f);
  u += 0x7fffu + ((u >> 16) & 1u);          // RTNE
  return (u16)(u >> 16);
}
__device__ __forceinline__ u32 pkbf(float lo, float hi){   // 1 inst packed cvt
  u32 d;
  asm("v_cvt_pk_bf16_f32 %0, %1, %2" : "=v"(d) : "v"(lo), "v"(hi));
  return d;
}
__device__ __forceinline__ float lo2f(u32 w){ return __builtin_bit_cast(float, w << 16); }
__device__ __forceinline__ float hi2f(u32 w){ return __builtin_bit_cast(float, w & 0xffff0000u); }
__device__ __forceinline__ float bfu2f(u16 h){ return __builtin_bit_cast(float, (u32)h << 16); }
__device__ __forceinline__ float fsigmoid(float v){ return __fdividef(1.f, 1.f + __expf(-v)); }
__device__ __forceinline__ float fsilu(float v){ return __fdividef(v, 1.f + __expf(-v)); }

// ---------------- kernel 1: weight convert (dot + gate) into staging layout --------
__global__ __launch_bounds__(256) void wconv(const float* __restrict__ pk,
                                             const float* __restrict__ gk,
                                             u16* __restrict__ wsdot,   // 16 chunks
                                             u16* __restrict__ wsgate)  // 16 chunks
{
  int gid = blockIdx.x * 256 + threadIdx.x;   // 32768 = 128 blocks
  int t = gid >> 10, S = gid & 1023;
  int q = (S >> 2) & 15, pp = S & 3, w8 = (S >> 6) & 7, rb = S >> 9;
  int n  = rb * 128 + w8 * 16 + q;
  int kq = pp ^ ((q >> 1) & 3);
  const float* W; int k0; u16* dst;
  if (t < 8)       { W = pk; k0 =       t      * 32 + kq * 8; dst = wsdot  + (size_t)t * 8192; }
  else if (t < 16) { W = pk; k0 = 512 + (t-8)  * 32 + kq * 8; dst = wsdot  + (size_t)t * 8192; }
  else             { W = gk; k0 =       (t-16) * 32 + kq * 8; dst = wsgate + (size_t)(t-16) * 8192; }
  u32 ow[4];
  #pragma unroll
  for (int e = 0; e < 4; ++e) {
    float f0 = W[(size_t)(k0 + 2*e)     * 256 + n];
    float f1 = W[(size_t)(k0 + 2*e + 1) * 256 + n];
    ow[e] = (u32)f2bf(f0) | ((u32)f2bf(f1) << 16);
  }
  *(u32x4*)(dst + (size_t)S * 8) = (u32x4){ow[0], ow[1], ow[2], ow[3]};
}

// ---------------- kernel 2: per-(b,h) partial sums of h_norm over w ----------------
__global__ __launch_bounds__(256) void ln_partial(const float* __restrict__ x,
                                                  const float* __restrict__ g,
                                                  const float* __restrict__ bt,
                                                  float* __restrict__ partial) // [768][256]
{
  const int bh = blockIdx.x;
  const int tid = threadIdx.x;
  const int wv = tid >> 6, lane = tid & 63;
  const float* xrow = x + (size_t)bh * 96 * 256;
  __shared__ float red[4][256];

  f32x4 gv = *(const f32x4*)(g  + lane * 4);
  f32x4 bv = *(const f32x4*)(bt + lane * 4);
  f32x4 acc = {0.f, 0.f, 0.f, 0.f};

  for (int w = wv; w < 96; w += 4) {
    f32x4 v = *(const f32x4*)(xrow + w * 256 + lane * 4);
    float s  = v[0] + v[1] + v[2] + v[3];
    float s2 = v[0]*v[0] + v[1]*v[1] + v[2]*v[2] + v[3]*v[3];
    #pragma unroll
    for (int m = 1; m < 64; m <<= 1) { s += __shfl_xor(s, m); s2 += __shfl_xor(s2, m); }
    float mu  = s * (1.f / 256.f);
    float var = s2 * (1.f / 256.f) - mu * mu;
    float rs  = rsqrtf(var + LN_EPS);
    #pragma unroll
    for (int j = 0; j < 4; ++j) acc[j] += (v[j] - mu) * rs * gv[j] + bv[j];
  }
  *(f32x4*)(&red[wv][lane * 4]) = acc;
  __syncthreads();
  float s = red[0][tid] + red[1][tid] + red[2][tid] + red[3][tid];
  partial[(size_t)bh * 256 + tid] = s;
}

// ---------------- kernel 3: reduce rows -> spatial mean [8][258] (wrap-padded) -----
__global__ __launch_bounds__(256) void ln_mean(const float* __restrict__ partial,
                                               float* __restrict__ mean)
{
  int b = blockIdx.x, c = threadIdx.x;
  float s = 0.f;
  for (int h = 0; h < 96; ++h) s += partial[((size_t)b * 96 + h) * 256 + c];
  float m = s * (1.f / 9216.f);
  mean[b * 258 + c] = m;
  if (c < 2) mean[b * 258 + 256 + c] = m;
}

// ---------------- kernel 4: fold wedge into per-batch weights ----------------------
__global__ __launch_bounds__(256) void wfold(const float* __restrict__ pk,
                                             const float* __restrict__ meang,
                                             u16* __restrict__ wsW)
{
  __shared__ float msh[256];
  int gid = blockIdx.x * 256 + threadIdx.x;   // 65536 = 256 blocks
  int chunk = gid >> 10;                      // 0..63 (uniform per block)
  int b = chunk >> 3, j = chunk & 7;
  msh[threadIdx.x] = meang[b * 258 + threadIdx.x];
  __syncthreads();
  int S = gid & 1023;
  int q = (S >> 2) & 15, pp = S & 3, w8 = (S >> 6) & 7, rb = S >> 9;
  int n  = rb * 128 + w8 * 16 + q;
  int kq = pp ^ ((q >> 1) & 3);
  u32 ow[4];
  #pragma unroll
  for (int e = 0; e < 4; ++e) {
    float r[2];
    #pragma unroll
    for (int hh = 0; hh < 2; ++hh) {
      int c = j * 32 + kq * 8 + 2 * e + hh;
      int cm1 = (c + 255) & 255, cm2 = (c + 254) & 255;
      int cp1 = (c + 1) & 255,   cp2 = (c + 2) & 255;
      r[hh] = msh[cm1] * pk[(size_t)(256 + cm1) * 256 + n]
            - msh[cp1] * pk[(size_t)(256 + c)   * 256 + n]
            + msh[cm2] * pk[(size_t)(768 + cm2) * 256 + n]
            - msh[cp2] * pk[(size_t)(768 + c)   * 256 + n];
    }
    ow[e] = (u32)f2bf(r[0]) | ((u32)f2bf(r[1]) << 16);
  }
  *(u32x4*)(wsW + (size_t)chunk * 8192 + (size_t)S * 8) = (u32x4){ow[0], ow[1], ow[2], ow[3]};
}

// ---------------- kernel 5: fused main ---------------------------------------------
// r7 skeleton + depth-2 register prefetch ring (chunk parity -> named breg set;
// writeB consumes a set loaded one full iteration earlier) + 2-pass preproc
// (lower peak VGPR; x re-read is L2-hot).
__global__ __launch_bounds__(512, 4) void fused(
    const float* __restrict__ x,
    const float* __restrict__ lng, const float* __restrict__ lnb,
    const u16* __restrict__ wsdot, const u16* __restrict__ wsW,
    const u16* __restrict__ wsgate,
    const float* __restrict__ pbias, const float* __restrict__ gbias,
    const float* __restrict__ gamma, const float* __restrict__ meang,
    float* __restrict__ out)
{
  __shared__ u16 hn[MROW * HSTR];       // 33792 B  h_norm bf16 (persists)
  __shared__ u16 afg[2][MROW * ASTR];   // 10240 B  A chunk dbuf (segs 0,1,4)
  __shared__ u16 Bl [2][8192];          // 32768 B  B chunk dbuf
  __shared__ float msh[258];            //  1032 B  spatial mean (wrap-padded)

  const int tid  = threadIdx.x;
  const long pix0 = (long)blockIdx.x * MROW;
  const int bat  = (int)(pix0 / HWPIX);      // 9216 % 64 == 0

  const int wave = tid >> 6, lane = tid & 63;
  const int wr = wave & 1, wc = wave >> 1;       // 2x4 wave grid
  const int fr = lane & 15, kq = lane >> 4;
  const int bswz = (kq ^ ((fr >> 1) & 3)) * 8;
  const int br = tid >> 3, bo = (tid & 7) * 4;   // feats build: row, 4-ch slice

  f32x4 acc[2][4];
  #pragma unroll
  for (int i = 0; i < 2; ++i)
    #pragma unroll
    for (int j = 0; j < 4; ++j) acc[i][j] = (f32x4){0.f, 0.f, 0.f, 0.f};
  u32 gfp[2][4][2];

  // ---- B staging: depth-2 ring. Chunk c lives in reg set (c&1). ----
  u32x4 brA0, brA1, brB0, brB1;
  auto sgptr = [&](auto SG) -> const u16* {
    constexpr int sg = decltype(SG)::value;
    if constexpr      (sg == 0) return wsdot;
    else if constexpr (sg == 1) return wsdot + 8 * 8192;
    else if constexpr (sg == 2) return wsW + (size_t)bat * 65536;
    else if constexpr (sg == 3) return wsgate;
    else                        return wsgate + 8 * 8192;
  };
  auto loadB = [&](auto SG, int jn, auto SET) {
    const u16* src = sgptr(SG) + (size_t)jn * 8192 + tid * 8;
    if constexpr (decltype(SET)::value == 0) {
      brA0 = *(const u32x4*)(src);
      brA1 = *(const u32x4*)(src + 4096);
    } else {
      brB0 = *(const u32x4*)(src);
      brB1 = *(const u32x4*)(src + 4096);
    }
  };
  auto writeB = [&](auto SET, int buf) {
    if constexpr (decltype(SET)::value == 0) {
      *(u32x4*)(&Bl[buf][tid * 8])        = brA0;
      *(u32x4*)(&Bl[buf][tid * 8 + 4096]) = brA1;
    } else {
      *(u32x4*)(&Bl[buf][tid * 8])        = brB0;
      *(u32x4*)(&Bl[buf][tid * 8 + 4096]) = brB1;
    }
  };

  loadB(IC<0>{}, 0, IC<0>{});         // chunk 0 -> set 0
  loadB(IC<0>{}, 1, IC<1>{});         // chunk 1 -> set 1

  if (tid < 258) msh[tid] = meang[bat * 258 + tid];

  float pbv[4];
  #pragma unroll
  for (int nt = 0; nt < 4; ++nt) pbv[nt] = pbias[wc * 64 + nt * 16 + fr];

  // ---- preproc (2-pass): LN -> hn (8 lanes/pixel, 32 ch each) ----
  {
    const int p = tid >> 3, o = tid & 7;
    const float* xp = x + (pix0 + p) * 256 + o * 32;
    float s = 0.f, s2 = 0.f;
    #pragma unroll
    for (int i = 0; i < 8; ++i) {
      f32x4 v = *(const f32x4*)(xp + i * 4);
      s  += v[0] + v[1] + v[2] + v[3];
      s2 += v[0]*v[0] + v[1]*v[1] + v[2]*v[2] + v[3]*v[3];
    }
    s += __shfl_xor(s, 1); s2 += __shfl_xor(s2, 1);
    s += __shfl_xor(s, 2); s2 += __shfl_xor(s2, 2);
    s += __shfl_xor(s, 4); s2 += __shfl_xor(s2, 4);
    float mu  = s * (1.f / 256.f);
    float var = s2 * (1.f / 256.f) - mu * mu;
    float rs  = rsqrtf(var + LN_EPS);

    const float* gp = lng + o * 32;
    const float* bp = lnb + o * 32;
    u16* zd = hn + p * HSTR + o * 32;
    #pragma unroll
    for (int i = 0; i < 8; ++i) {
      f32x4 v  = *(const f32x4*)(xp + i * 4);     // L2-hot reload
      f32x4 gg = *(const f32x4*)(gp + i * 4);
      f32x4 bb = *(const f32x4*)(bp + i * 4);
      float h0 = (v[0] - mu) * rs * gg[0] + bb[0];
      float h1 = (v[1] - mu) * rs * gg[1] + bb[1];
      float h2 = (v[2] - mu) * rs * gg[2] + bb[2];
      float h3 = (v[3] - mu) * rs * gg[3] + bb[3];
      u32 d0 = pkbf(h0, h1);
      u32 d1 = pkbf(h2, h3);
      *(u32*)(zd + i * 4)     = d0;
      *(u32*)(zd + i * 4 + 2) = d1;
      if (i == 0 && o == 0) *(u32*)(hn + p * HSTR + 256) = d0;  // wrap pad
    }
  }

  // dot feats for shift s (compile-time), window w -> afg[buf]
  auto featsD = [&](auto SC, int w, int buf) {
    constexpr int s = decltype(SC)::value;
    const int cc = w * 32 + bo;
    const u16* zp = hn + br * HSTR + cc;
    u32 a0 = *(const u32*)(zp);
    u32 a1 = *(const u32*)(zp + 2);
    u32 a2 = *(const u32*)(zp + 4);
    float h0 = lo2f(a0), h1 = hi2f(a0), h2 = lo2f(a1);
    float h3 = hi2f(a1), h4 = lo2f(a2), h5 = hi2f(a2);
    float m0 = msh[cc + s], m1 = msh[cc + s + 1];
    float m2 = msh[cc + s + 2], m3 = msh[cc + s + 3];
    float t0, t1, t2, t3;
    if constexpr (s == 1) { t0 = h1; t1 = h2; t2 = h3; t3 = h4; }
    else                  { t0 = h2; t1 = h3; t2 = h4; t3 = h5; }
    float r0 = fsilu(h0 * (t0 - m0));
    float r1 = fsilu(h1 * (t1 - m1));
    float r2 = fsilu(h2 * (t2 - m2));
    float r3 = fsilu(h3 * (t3 - m3));
    *(u32*)(&afg[buf][br * ASTR + bo])     = pkbf(r0, r1);
    *(u32*)(&afg[buf][br * ASTR + bo + 2]) = pkbf(r2, r3);
  };

  // g_feat chunk cg (compile-time) from packed regs into afg
  auto gfcopy = [&](auto CGC, int buf) {
    constexpr int cg = decltype(CGC)::value;
    constexpr int par = cg & 1;
    if (wc == (cg >> 1)) {
      #pragma unroll
      for (int v = 0; v < 2; ++v) {
        #pragma unroll
        for (int ai = 0; ai < 2; ++ai)
          #pragma unroll
          for (int rp = 0; rp < 2; ++rp) {
            u32 pw = gfp[ai][par * 2 + v][rp];
            int row0 = wr * 32 + ai * 16 + kq * 4 + rp * 2;
            afg[buf][row0 * ASTR + v * 16 + fr]       = (u16)pw;
            afg[buf][(row0 + 1) * ASTR + v * 16 + fr] = (u16)(pw >> 16);
          }
      }
    }
  };

  auto domfma = [&](const u16* abase, int astr, int buf) {
    bf16x8 av0 = *(const bf16x8*)(abase);
    bf16x8 av1 = *(const bf16x8*)(abase + 16 * astr);
    const u16* bp = &Bl[buf][wc * 2048 + fr * 32 + bswz];
    #pragma unroll
    for (int nt = 0; nt < 4; ++nt) {
      bf16x8 bv = *(const bf16x8*)(bp + nt * 512);
      acc[0][nt] = __builtin_amdgcn_mfma_f32_16x16x32_bf16(av0, bv, acc[0][nt], 0, 0, 0);
      acc[1][nt] = __builtin_amdgcn_mfma_f32_16x16x32_bf16(av1, bv, acc[1][nt], 0, 0, 0);
    }
  };

  __syncthreads();                    // hn, msh visible
  writeB(IC<0>{}, 0);                 // Bl[0] = chunk 0 (loaded long ago)
  featsD(IC<1>{}, 0, 0);              // afg[0] = dot s=1 window 0
  __syncthreads();                    // Bl[0], afg[0] visible
  // state: set1 holds chunk 1; next load = chunk 2 -> set 0.

  auto stepfn = [&](auto SEGC, auto JC) {
    constexpr int SEG = decltype(SEGC)::value;
    constexpr int j   = decltype(JC)::value;
    constexpr int t   = SEG * 8 + j;
    constexpr int cb  = t & 1, nb = cb ^ 1;
    constexpr int l   = t + 2;                    // chunk to load -> set (l&1)==(t&1)
    if constexpr (l < 40) loadB(IC<(l >> 3)>{}, l & 7, IC<l & 1>{});
    constexpr int u    = t + 1;                   // chunk to build+write
    constexpr int useg = u >> 3;
    if constexpr (u < 40) {
      if constexpr      (useg == 0) featsD(IC<1>{}, u & 7, nb);
      else if constexpr (useg == 1) featsD(IC<2>{}, u & 7, nb);
      else if constexpr (useg == 4) gfcopy(IC<u - 32>{}, nb);
      writeB(IC<u & 1>{}, nb);        // set loaded one full iteration ago
    }
    if constexpr (SEG == 0 || SEG == 1 || SEG == 4)
      domfma(&afg[cb][(wr * 32 + fr) * ASTR + kq * 8], ASTR, cb);
    else
      domfma(&hn[(wr * 32 + fr) * HSTR + j * 32 + kq * 8], HSTR, cb);
    if constexpr (t == 23) {          // end of GEMM1: fold to packed bf16 g_feat
      #pragma unroll
      for (int nt = 0; nt < 4; ++nt)
        #pragma unroll
        for (int ai = 0; ai < 2; ++ai) {
          f32x4 a = acc[ai][nt];
          gfp[ai][nt][0] = pkbf(a[0] + pbv[nt], a[1] + pbv[nt]);
          gfp[ai][nt][1] = pkbf(a[2] + pbv[nt], a[3] + pbv[nt]);
          acc[ai][nt] = (f32x4){0.f, 0.f, 0.f, 0.f};
        }
    }
    __syncthreads();
  };
  auto runseg = [&](auto SEGC) {
    stepfn(SEGC, IC<0>{}); stepfn(SEGC, IC<1>{});
    stepfn(SEGC, IC<2>{}); stepfn(SEGC, IC<3>{});
    stepfn(SEGC, IC<4>{}); stepfn(SEGC, IC<5>{});
    stepfn(SEGC, IC<6>{}); stepfn(SEGC, IC<7>{});
  };
  runseg(IC<0>{}); runseg(IC<1>{}); runseg(IC<2>{});
  runseg(IC<3>{}); runseg(IC<4>{});

  // ---- final epilogue: alpha, silu, LayerScale, residual ----
  float gbv[4], gmv[4];
  #pragma unroll
  for (int nt = 0; nt < 4; ++nt) {
    int col = wc * 64 + nt * 16 + fr;
    gbv[nt] = gbias[col]; gmv[nt] = gamma[col];
  }
  #pragma unroll
  for (int ai = 0; ai < 2; ++ai)
    #pragma unroll
    for (int rr = 0; rr < 4; ++rr) {
      const int row = wr * 32 + ai * 16 + kq * 4 + rr;
      const long pix = pix0 + row;
      #pragma unroll
      for (int nt = 0; nt < 4; ++nt) {
        int col = wc * 64 + nt * 16 + fr;
        float xv = x[pix * 256 + col];
        float hh = bfu2f(hn[row * HSTR + col]);
        u32 pw = gfp[ai][nt][rr >> 1];
        float gfv = bfu2f((u16)((rr & 1) ? (pw >> 16) : pw));
        float al = fsigmoid(acc[ai][nt][rr] + gbv[nt]);
        out[pix * 256 + col] = xv + (fsilu(hh) + al * gfv) * gmv[nt];
      }
    }
}

extern "C" void kernel_launch(void* const* d_in, const int* in_sizes, int n_in,
                              void* d_out, int out_size, void* d_ws, size_t ws_size,
                              hipStream_t stream) {
  const float* x     = (const float*)d_in[0];
  const float* lng   = (const float*)d_in[1];
  const float* lnb   = (const float*)d_in[2];
  const float* pk    = (const float*)d_in[3];
  const float* pbias = (const float*)d_in[4];
  const float* gk    = (const float*)d_in[5];
  const float* gbias = (const float*)d_in[6];
  const float* gamma = (const float*)d_in[7];
  float* out = (float*)d_out;

  char* ws = (char*)d_ws;
  u16*   wsdot   = (u16*)ws;                       // 262144 B (16 chunks)
  u16*   wsgate  = (u16*)(ws + 262144);            // 262144 B (16 chunks)
  float* meang   = (float*)(ws + 524288);          // 8256 B
  u16*   wsW     = (u16*)(ws + 532544);            // 1048576 B (64 chunks, per-batch W')
  float* partial = (float*)(ws + 532544);          // 786432 B — dead before wfold writes W'

  wconv<<<128, 256, 0, stream>>>(pk, gk, wsdot, wsgate);
  ln_partial<<<768, 256, 0, stream>>>(x, lng, lnb, partial);
  ln_mean<<<8, 256, 0, stream>>>(partial, meang);
  wfold<<<256, 256, 0, stream>>>(pk, meang, wsW);
  fused<<<NPIX / MROW, 512, 0, stream>>>(x, lng, lnb, wsdot, wsW, wsgate,
                                         pbias, gbias, gamma, meang, out);
}

// Round 9
// 150.796 us; speedup vs baseline: 3.5272x; 1.0514x over previous
//
#include <hip/hip_runtime.h>
#include <hip/hip_bf16.h>

typedef unsigned short u16;
typedef unsigned int   u32;
typedef __attribute__((ext_vector_type(4))) float f32x4;
typedef __attribute__((ext_vector_type(4))) u32   u32x4;
typedef __attribute__((ext_vector_type(8))) short bf16x8;

#define HWPIX  9216
#define NPIX   73728
#define LN_EPS 1e-5f
#define MROW   64       // pixels per block
#define HSTR   264      // hn row stride (elems): 256 + 8 pad (incl. 2-ch wrap pad)
#define ASTR   40       // afg chunk row stride (elems): 32 + 8 pad

template<int N> struct IC { static constexpr int value = N; };

__device__ __forceinline__ u16 f2bf(float f){
  u32 u = __builtin_bit_cast(u32, f);
  u += 0x7fffu + ((u >> 16) & 1u);          // RTNE
  return (u16)(u >> 16);
}
__device__ __forceinline__ u32 pkbf(float lo, float hi){   // 1 inst packed cvt
  u32 d;
  asm("v_cvt_pk_bf16_f32 %0, %1, %2" : "=v"(d) : "v"(lo), "v"(hi));
  return d;
}
__device__ __forceinline__ float lo2f(u32 w){ return __builtin_bit_cast(float, w << 16); }
__device__ __forceinline__ float hi2f(u32 w){ return __builtin_bit_cast(float, w & 0xffff0000u); }
__device__ __forceinline__ float bfu2f(u16 h){ return __builtin_bit_cast(float, (u32)h << 16); }
__device__ __forceinline__ float fsigmoid(float v){ return __fdividef(1.f, 1.f + __expf(-v)); }
__device__ __forceinline__ float fsilu(float v){ return __fdividef(v, 1.f + __expf(-v)); }

// ---------------- kernel 1: weight convert (dot + gate) into staging layout --------
__global__ __launch_bounds__(256) void wconv(const float* __restrict__ pk,
                                             const float* __restrict__ gk,
                                             u16* __restrict__ wsdot,   // 16 chunks
                                             u16* __restrict__ wsgate)  // 16 chunks
{
  int gid = blockIdx.x * 256 + threadIdx.x;   // 32768 = 128 blocks
  int t = gid >> 10, S = gid & 1023;
  int q = (S >> 2) & 15, pp = S & 3, w8 = (S >> 6) & 7, rb = S >> 9;
  int n  = rb * 128 + w8 * 16 + q;
  int kq = pp ^ ((q >> 1) & 3);
  const float* W; int k0; u16* dst;
  if (t < 8)       { W = pk; k0 =       t      * 32 + kq * 8; dst = wsdot  + (size_t)t * 8192; }
  else if (t < 16) { W = pk; k0 = 512 + (t-8)  * 32 + kq * 8; dst = wsdot  + (size_t)t * 8192; }
  else             { W = gk; k0 =       (t-16) * 32 + kq * 8; dst = wsgate + (size_t)(t-16) * 8192; }
  u32 ow[4];
  #pragma unroll
  for (int e = 0; e < 4; ++e) {
    float f0 = W[(size_t)(k0 + 2*e)     * 256 + n];
    float f1 = W[(size_t)(k0 + 2*e + 1) * 256 + n];
    ow[e] = (u32)f2bf(f0) | ((u32)f2bf(f1) << 16);
  }
  *(u32x4*)(dst + (size_t)S * 8) = (u32x4){ow[0], ow[1], ow[2], ow[3]};
}

// ---------------- kernel 2: per-(b,h) partial sums of h_norm over w ----------------
__global__ __launch_bounds__(256) void ln_partial(const float* __restrict__ x,
                                                  const float* __restrict__ g,
                                                  const float* __restrict__ bt,
                                                  float* __restrict__ partial) // [768][256]
{
  const int bh = blockIdx.x;
  const int tid = threadIdx.x;
  const int wv = tid >> 6, lane = tid & 63;
  const float* xrow = x + (size_t)bh * 96 * 256;
  __shared__ float red[4][256];

  f32x4 gv = *(const f32x4*)(g  + lane * 4);
  f32x4 bv = *(const f32x4*)(bt + lane * 4);
  f32x4 acc = {0.f, 0.f, 0.f, 0.f};

  for (int w = wv; w < 96; w += 4) {
    f32x4 v = *(const f32x4*)(xrow + w * 256 + lane * 4);
    float s  = v[0] + v[1] + v[2] + v[3];
    float s2 = v[0]*v[0] + v[1]*v[1] + v[2]*v[2] + v[3]*v[3];
    #pragma unroll
    for (int m = 1; m < 64; m <<= 1) { s += __shfl_xor(s, m); s2 += __shfl_xor(s2, m); }
    float mu  = s * (1.f / 256.f);
    float var = s2 * (1.f / 256.f) - mu * mu;
    float rs  = rsqrtf(var + LN_EPS);
    #pragma unroll
    for (int j = 0; j < 4; ++j) acc[j] += (v[j] - mu) * rs * gv[j] + bv[j];
  }
  *(f32x4*)(&red[wv][lane * 4]) = acc;
  __syncthreads();
  float s = red[0][tid] + red[1][tid] + red[2][tid] + red[3][tid];
  partial[(size_t)bh * 256 + tid] = s;
}

// ---------------- kernel 3: reduce rows -> spatial mean [8][258] (wrap-padded) -----
__global__ __launch_bounds__(256) void ln_mean(const float* __restrict__ partial,
                                               float* __restrict__ mean)
{
  int b = blockIdx.x, c = threadIdx.x;
  float s = 0.f;
  for (int h = 0; h < 96; ++h) s += partial[((size_t)b * 96 + h) * 256 + c];
  float m = s * (1.f / 9216.f);
  mean[b * 258 + c] = m;
  if (c < 2) mean[b * 258 + 256 + c] = m;
}

// ---------------- kernel 4: fold wedge into per-batch weights ----------------------
__global__ __launch_bounds__(256) void wfold(const float* __restrict__ pk,
                                             const float* __restrict__ meang,
                                             u16* __restrict__ wsW)
{
  __shared__ float msh[256];
  int gid = blockIdx.x * 256 + threadIdx.x;   // 65536 = 256 blocks
  int chunk = gid >> 10;                      // 0..63 (uniform per block)
  int b = chunk >> 3, j = chunk & 7;
  msh[threadIdx.x] = meang[b * 258 + threadIdx.x];
  __syncthreads();
  int S = gid & 1023;
  int q = (S >> 2) & 15, pp = S & 3, w8 = (S >> 6) & 7, rb = S >> 9;
  int n  = rb * 128 + w8 * 16 + q;
  int kq = pp ^ ((q >> 1) & 3);
  u32 ow[4];
  #pragma unroll
  for (int e = 0; e < 4; ++e) {
    float r[2];
    #pragma unroll
    for (int hh = 0; hh < 2; ++hh) {
      int c = j * 32 + kq * 8 + 2 * e + hh;
      int cm1 = (c + 255) & 255, cm2 = (c + 254) & 255;
      int cp1 = (c + 1) & 255,   cp2 = (c + 2) & 255;
      r[hh] = msh[cm1] * pk[(size_t)(256 + cm1) * 256 + n]
            - msh[cp1] * pk[(size_t)(256 + c)   * 256 + n]
            + msh[cm2] * pk[(size_t)(768 + cm2) * 256 + n]
            - msh[cp2] * pk[(size_t)(768 + c)   * 256 + n];
    }
    ow[e] = (u32)f2bf(r[0]) | ((u32)f2bf(r[1]) << 16);
  }
  *(u32x4*)(wsW + (size_t)chunk * 8192 + (size_t)S * 8) = (u32x4){ow[0], ow[1], ow[2], ow[3]};
}

// ---------------- kernel 5: fused main ---------------------------------------------
// r8 skeleton; ONLY change: domfma is issued BEFORE feats/gfcopy+writeB in each step,
// so each wave's producer VALU executes while its MFMAs drain on the matrix pipe
// (separate pipes). Buffers are disjoint (cb vs nb) -> no hazard; barrier unchanged.
__global__ __launch_bounds__(512, 4) void fused(
    const float* __restrict__ x,
    const float* __restrict__ lng, const float* __restrict__ lnb,
    const u16* __restrict__ wsdot, const u16* __restrict__ wsW,
    const u16* __restrict__ wsgate,
    const float* __restrict__ pbias, const float* __restrict__ gbias,
    const float* __restrict__ gamma, const float* __restrict__ meang,
    float* __restrict__ out)
{
  __shared__ u16 hn[MROW * HSTR];       // 33792 B  h_norm bf16 (persists)
  __shared__ u16 afg[2][MROW * ASTR];   // 10240 B  A chunk dbuf (segs 0,1,4)
  __shared__ u16 Bl [2][8192];          // 32768 B  B chunk dbuf
  __shared__ float msh[258];            //  1032 B  spatial mean (wrap-padded)

  const int tid  = threadIdx.x;
  const long pix0 = (long)blockIdx.x * MROW;
  const int bat  = (int)(pix0 / HWPIX);      // 9216 % 64 == 0

  const int wave = tid >> 6, lane = tid & 63;
  const int wr = wave & 1, wc = wave >> 1;       // 2x4 wave grid
  const int fr = lane & 15, kq = lane >> 4;
  const int bswz = (kq ^ ((fr >> 1) & 3)) * 8;
  const int br = tid >> 3, bo = (tid & 7) * 4;   // feats build: row, 4-ch slice

  f32x4 acc[2][4];
  #pragma unroll
  for (int i = 0; i < 2; ++i)
    #pragma unroll
    for (int j = 0; j < 4; ++j) acc[i][j] = (f32x4){0.f, 0.f, 0.f, 0.f};
  u32 gfp[2][4][2];

  // ---- B staging: depth-2 ring. Chunk c lives in reg set (c&1). ----
  u32x4 brA0, brA1, brB0, brB1;
  auto sgptr = [&](auto SG) -> const u16* {
    constexpr int sg = decltype(SG)::value;
    if constexpr      (sg == 0) return wsdot;
    else if constexpr (sg == 1) return wsdot + 8 * 8192;
    else if constexpr (sg == 2) return wsW + (size_t)bat * 65536;
    else if constexpr (sg == 3) return wsgate;
    else                        return wsgate + 8 * 8192;
  };
  auto loadB = [&](auto SG, int jn, auto SET) {
    const u16* src = sgptr(SG) + (size_t)jn * 8192 + tid * 8;
    if constexpr (decltype(SET)::value == 0) {
      brA0 = *(const u32x4*)(src);
      brA1 = *(const u32x4*)(src + 4096);
    } else {
      brB0 = *(const u32x4*)(src);
      brB1 = *(const u32x4*)(src + 4096);
    }
  };
  auto writeB = [&](auto SET, int buf) {
    if constexpr (decltype(SET)::value == 0) {
      *(u32x4*)(&Bl[buf][tid * 8])        = brA0;
      *(u32x4*)(&Bl[buf][tid * 8 + 4096]) = brA1;
    } else {
      *(u32x4*)(&Bl[buf][tid * 8])        = brB0;
      *(u32x4*)(&Bl[buf][tid * 8 + 4096]) = brB1;
    }
  };

  loadB(IC<0>{}, 0, IC<0>{});         // chunk 0 -> set 0
  loadB(IC<0>{}, 1, IC<1>{});         // chunk 1 -> set 1

  if (tid < 258) msh[tid] = meang[bat * 258 + tid];

  float pbv[4];
  #pragma unroll
  for (int nt = 0; nt < 4; ++nt) pbv[nt] = pbias[wc * 64 + nt * 16 + fr];

  // ---- preproc (2-pass): LN -> hn (8 lanes/pixel, 32 ch each) ----
  {
    const int p = tid >> 3, o = tid & 7;
    const float* xp = x + (pix0 + p) * 256 + o * 32;
    float s = 0.f, s2 = 0.f;
    #pragma unroll
    for (int i = 0; i < 8; ++i) {
      f32x4 v = *(const f32x4*)(xp + i * 4);
      s  += v[0] + v[1] + v[2] + v[3];
      s2 += v[0]*v[0] + v[1]*v[1] + v[2]*v[2] + v[3]*v[3];
    }
    s += __shfl_xor(s, 1); s2 += __shfl_xor(s2, 1);
    s += __shfl_xor(s, 2); s2 += __shfl_xor(s2, 2);
    s += __shfl_xor(s, 4); s2 += __shfl_xor(s2, 4);
    float mu  = s * (1.f / 256.f);
    float var = s2 * (1.f / 256.f) - mu * mu;
    float rs  = rsqrtf(var + LN_EPS);

    const float* gp = lng + o * 32;
    const float* bp = lnb + o * 32;
    u16* zd = hn + p * HSTR + o * 32;
    #pragma unroll
    for (int i = 0; i < 8; ++i) {
      f32x4 v  = *(const f32x4*)(xp + i * 4);     // L2-hot reload
      f32x4 gg = *(const f32x4*)(gp + i * 4);
      f32x4 bb = *(const f32x4*)(bp + i * 4);
      float h0 = (v[0] - mu) * rs * gg[0] + bb[0];
      float h1 = (v[1] - mu) * rs * gg[1] + bb[1];
      float h2 = (v[2] - mu) * rs * gg[2] + bb[2];
      float h3 = (v[3] - mu) * rs * gg[3] + bb[3];
      u32 d0 = pkbf(h0, h1);
      u32 d1 = pkbf(h2, h3);
      *(u32*)(zd + i * 4)     = d0;
      *(u32*)(zd + i * 4 + 2) = d1;
      if (i == 0 && o == 0) *(u32*)(hn + p * HSTR + 256) = d0;  // wrap pad
    }
  }

  // dot feats for shift s (compile-time), window w -> afg[buf]
  auto featsD = [&](auto SC, int w, int buf) {
    constexpr int s = decltype(SC)::value;
    const int cc = w * 32 + bo;
    const u16* zp = hn + br * HSTR + cc;
    u32 a0 = *(const u32*)(zp);
    u32 a1 = *(const u32*)(zp + 2);
    u32 a2 = *(const u32*)(zp + 4);
    float h0 = lo2f(a0), h1 = hi2f(a0), h2 = lo2f(a1);
    float h3 = hi2f(a1), h4 = lo2f(a2), h5 = hi2f(a2);
    float m0 = msh[cc + s], m1 = msh[cc + s + 1];
    float m2 = msh[cc + s + 2], m3 = msh[cc + s + 3];
    float t0, t1, t2, t3;
    if constexpr (s == 1) { t0 = h1; t1 = h2; t2 = h3; t3 = h4; }
    else                  { t0 = h2; t1 = h3; t2 = h4; t3 = h5; }
    float r0 = fsilu(h0 * (t0 - m0));
    float r1 = fsilu(h1 * (t1 - m1));
    float r2 = fsilu(h2 * (t2 - m2));
    float r3 = fsilu(h3 * (t3 - m3));
    *(u32*)(&afg[buf][br * ASTR + bo])     = pkbf(r0, r1);
    *(u32*)(&afg[buf][br * ASTR + bo + 2]) = pkbf(r2, r3);
  };

  // g_feat chunk cg (compile-time) from packed regs into afg
  auto gfcopy = [&](auto CGC, int buf) {
    constexpr int cg = decltype(CGC)::value;
    constexpr int par = cg & 1;
    if (wc == (cg >> 1)) {
      #pragma unroll
      for (int v = 0; v < 2; ++v) {
        #pragma unroll
        for (int ai = 0; ai < 2; ++ai)
          #pragma unroll
          for (int rp = 0; rp < 2; ++rp) {
            u32 pw = gfp[ai][par * 2 + v][rp];
            int row0 = wr * 32 + ai * 16 + kq * 4 + rp * 2;
            afg[buf][row0 * ASTR + v * 16 + fr]       = (u16)pw;
            afg[buf][(row0 + 1) * ASTR + v * 16 + fr] = (u16)(pw >> 16);
          }
      }
    }
  };

  auto domfma = [&](const u16* abase, int astr, int buf) {
    bf16x8 av0 = *(const bf16x8*)(abase);
    bf16x8 av1 = *(const bf16x8*)(abase + 16 * astr);
    const u16* bp = &Bl[buf][wc * 2048 + fr * 32 + bswz];
    #pragma unroll
    for (int nt = 0; nt < 4; ++nt) {
      bf16x8 bv = *(const bf16x8*)(bp + nt * 512);
      acc[0][nt] = __builtin_amdgcn_mfma_f32_16x16x32_bf16(av0, bv, acc[0][nt], 0, 0, 0);
      acc[1][nt] = __builtin_amdgcn_mfma_f32_16x16x32_bf16(av1, bv, acc[1][nt], 0, 0, 0);
    }
  };

  __syncthreads();                    // hn, msh visible
  writeB(IC<0>{}, 0);                 // Bl[0] = chunk 0 (loaded long ago)
  featsD(IC<1>{}, 0, 0);              // afg[0] = dot s=1 window 0
  __syncthreads();                    // Bl[0], afg[0] visible
  // state: set1 holds chunk 1; next load = chunk 2 -> set 0.

  auto stepfn = [&](auto SEGC, auto JC) {
    constexpr int SEG = decltype(SEGC)::value;
    constexpr int j   = decltype(JC)::value;
    constexpr int t   = SEG * 8 + j;
    constexpr int cb  = t & 1, nb = cb ^ 1;
    constexpr int l   = t + 2;                    // chunk to load -> set (l&1)==(t&1)
    if constexpr (l < 40) loadB(IC<(l >> 3)>{}, l & 7, IC<l & 1>{});
    // ---- MFMA first: issue the burst, then produce next chunk under it ----
    if constexpr (SEG == 0 || SEG == 1 || SEG == 4)
      domfma(&afg[cb][(wr * 32 + fr) * ASTR + kq * 8], ASTR, cb);
    else
      domfma(&hn[(wr * 32 + fr) * HSTR + j * 32 + kq * 8], HSTR, cb);
    constexpr int u    = t + 1;                   // chunk to build+write
    constexpr int useg = u >> 3;
    if constexpr (u < 40) {
      if constexpr      (useg == 0) featsD(IC<1>{}, u & 7, nb);
      else if constexpr (useg == 1) featsD(IC<2>{}, u & 7, nb);
      else if constexpr (useg == 4) gfcopy(IC<u - 32>{}, nb);
      writeB(IC<u & 1>{}, nb);        // set loaded one full iteration ago
    }
    if constexpr (t == 23) {          // end of GEMM1: fold to packed bf16 g_feat
      #pragma unroll
      for (int nt = 0; nt < 4; ++nt)
        #pragma unroll
        for (int ai = 0; ai < 2; ++ai) {
          f32x4 a = acc[ai][nt];
          gfp[ai][nt][0] = pkbf(a[0] + pbv[nt], a[1] + pbv[nt]);
          gfp[ai][nt][1] = pkbf(a[2] + pbv[nt], a[3] + pbv[nt]);
          acc[ai][nt] = (f32x4){0.f, 0.f, 0.f, 0.f};
        }
    }
    __syncthreads();
  };
  auto runseg = [&](auto SEGC) {
    stepfn(SEGC, IC<0>{}); stepfn(SEGC, IC<1>{});
    stepfn(SEGC, IC<2>{}); stepfn(SEGC, IC<3>{});
    stepfn(SEGC, IC<4>{}); stepfn(SEGC, IC<5>{});
    stepfn(SEGC, IC<6>{}); stepfn(SEGC, IC<7>{});
  };
  runseg(IC<0>{}); runseg(IC<1>{}); runseg(IC<2>{});
  runseg(IC<3>{}); runseg(IC<4>{});

  // ---- final epilogue: alpha, silu, LayerScale, residual ----
  float gbv[4], gmv[4];
  #pragma unroll
  for (int nt = 0; nt < 4; ++nt) {
    int col = wc * 64 + nt * 16 + fr;
    gbv[nt] = gbias[col]; gmv[nt] = gamma[col];
  }
  #pragma unroll
  for (int ai = 0; ai < 2; ++ai)
    #pragma unroll
    for (int rr = 0; rr < 4; ++rr) {
      const int row = wr * 32 + ai * 16 + kq * 4 + rr;
      const long pix = pix0 + row;
      #pragma unroll
      for (int nt = 0; nt < 4; ++nt) {
        int col = wc * 64 + nt * 16 + fr;
        float xv = x[pix * 256 + col];
        float hh = bfu2f(hn[row * HSTR + col]);
        u32 pw = gfp[ai][nt][rr >> 1];
        float gfv = bfu2f((u16)((rr & 1) ? (pw >> 16) : pw));
        float al = fsigmoid(acc[ai][nt][rr] + gbv[nt]);
        out[pix * 256 + col] = xv + (fsilu(hh) + al * gfv) * gmv[nt];
      }
    }
}

extern "C" void kernel_launch(void* const* d_in, const int* in_sizes, int n_in,
                              void* d_out, int out_size, void* d_ws, size_t ws_size,
                              hipStream_t stream) {
  const float* x     = (const float*)d_in[0];
  const float* lng   = (const float*)d_in[1];
  const float* lnb   = (const float*)d_in[2];
  const float* pk    = (const float*)d_in[3];
  const float* pbias = (const float*)d_in[4];
  const float* gk    = (const float*)d_in[5];
  const float* gbias = (const float*)d_in[6];
  const float* gamma = (const float*)d_in[7];
  float* out = (float*)d_out;

  char* ws = (char*)d_ws;
  u16*   wsdot   = (u16*)ws;                       // 262144 B (16 chunks)
  u16*   wsgate  = (u16*)(ws + 262144);            // 262144 B (16 chunks)
  float* meang   = (float*)(ws + 524288);          // 8256 B
  u16*   wsW     = (u16*)(ws + 532544);            // 1048576 B (64 chunks, per-batch W')
  float* partial = (float*)(ws + 532544);          // 786432 B — dead before wfold writes W'

  wconv<<<128, 256, 0, stream>>>(pk, gk, wsdot, wsgate);
  ln_partial<<<768, 256, 0, stream>>>(x, lng, lnb, partial);
  ln_mean<<<8, 256, 0, stream>>>(partial, meang);
  wfold<<<256, 256, 0, stream>>>(pk, meang, wsW);
  fused<<<NPIX / MROW, 512, 0, stream>>>(x, lng, lnb, wsdot, wsW, wsgate,
                                         pbias, gbias, gamma, meang, out);
}